// Round 11
// baseline (127.386 us; speedup 1.0000x reference)
//
#include <hip/hip_runtime.h>

#define NB 64
#define LC 1024
#define LQ 128
#define DD 128
#define NEG_BIG 1.0e12f

typedef __attribute__((ext_vector_type(8))) short short8;
typedef __attribute__((ext_vector_type(4))) unsigned short ushort4v;
typedef __attribute__((ext_vector_type(4))) float floatx4;

__device__ __forceinline__ unsigned short f2bf(float f) {
  union { float f; unsigned int u; } v;
  v.f = f;
  const unsigned int r = v.u + 0x7FFFu + ((v.u >> 16) & 1u);
  return (unsigned short)(r >> 16);
}
__device__ __forceinline__ float bf2f(unsigned int u) {
  union { unsigned int u; float f; } v;
  v.u = u << 16;
  return v.f;
}

// ---------------------------------------------------------------------------
// K_score (MFMA), per (b, 128-c tile):
//   S = a_cont + a_ques + (xc.W2) xq^T ; a_cont AND a_ques inline;
//   xcT emitted from LDS tile.
//   - q-masked softmax -> sbarb bf16 [c][q] + out_sbar f32 (both from ONE
//     full-width LDS tile phase, coalesced)
//   - Pb[b][q][c] = (c<clen ? exp(S) : 0) bf16 (ONE phase) + colsum partials
// ---------------------------------------------------------------------------
#define PADW 136

__global__ __launch_bounds__(512) void k_score(
    const float* __restrict__ xc, const float* __restrict__ xq,
    const float* __restrict__ w2, const float* __restrict__ W0,
    const float* __restrict__ W1, const int* __restrict__ qlen_p,
    const int* __restrict__ clen_p, float* __restrict__ out_sbar,
    unsigned short* __restrict__ Pb, float* __restrict__ colsum_part,
    unsigned short* __restrict__ xcT, unsigned short* __restrict__ sbarb) {
  __shared__ __align__(16) unsigned short smem[2 * 128 * PADW];  // 69632 B
  __shared__ float a_cont_s[128];
  __shared__ float a_ques_s[128];
  unsigned short* xcs = smem;                  // plain xc tile [128][PADW]
  unsigned short* xqs = smem + 128 * PADW;     // xq*W2 tile [128][PADW]
  unsigned short* ptile = smem + 128 * PADW;   // [128][136] reuse after MFMA

  const int b = blockIdx.x >> 3;
  const int ct = blockIdx.x & 7;
  const int c0 = ct << 7;
  const int t = threadIdx.x;
  const int w = t >> 6, lane = t & 63;
  const int frow = lane & 15;
  const int kb = lane >> 4;

  const float* xc_blk = xc + ((size_t)b * LC + c0) * DD;
  const float* xq_b = xq + (size_t)b * LQ * DD;

  const int u = t & 15;
  const float4 w0a = *(const float4*)(W0 + (u << 3));
  const float4 w0b = *(const float4*)(W0 + (u << 3) + 4);
  const float4 w1a = *(const float4*)(W1 + (u << 3));
  const float4 w1b = *(const float4*)(W1 + (u << 3) + 4);
  const float4 w2a = *(const float4*)(w2 + (u << 3));
  const float4 w2b = *(const float4*)(w2 + (u << 3) + 4);

  // ---- stage xc (bf16, + a_cont partials) and xq*W2 (bf16, + a_ques) ----
#pragma unroll
  for (int i = 0; i < 4; ++i) {
    const int row = (t >> 4) + (i << 5);
    {
      const float4 v0 = *(const float4*)(xc_blk + (size_t)row * DD + (u << 3));
      const float4 v1 = *(const float4*)(xc_blk + (size_t)row * DD + (u << 3) + 4);
      short8 pk;
      pk[0] = (short)f2bf(v0.x); pk[1] = (short)f2bf(v0.y);
      pk[2] = (short)f2bf(v0.z); pk[3] = (short)f2bf(v0.w);
      pk[4] = (short)f2bf(v1.x); pk[5] = (short)f2bf(v1.y);
      pk[6] = (short)f2bf(v1.z); pk[7] = (short)f2bf(v1.w);
      *(short8*)(xcs + row * PADW + (u << 3)) = pk;
      float pd = v0.x * w0a.x + v0.y * w0a.y + v0.z * w0a.z + v0.w * w0a.w +
                 v1.x * w0b.x + v1.y * w0b.y + v1.z * w0b.z + v1.w * w0b.w;
#pragma unroll
      for (int msk = 8; msk >= 1; msk >>= 1) pd += __shfl_xor(pd, msk, 64);
      if ((lane & 15) == 0) a_cont_s[row] = pd;
    }
    {
      const float4 v0 = *(const float4*)(xq_b + (size_t)row * DD + (u << 3));
      const float4 v1 = *(const float4*)(xq_b + (size_t)row * DD + (u << 3) + 4);
      float pq = v0.x * w1a.x + v0.y * w1a.y + v0.z * w1a.z + v0.w * w1a.w +
                 v1.x * w1b.x + v1.y * w1b.y + v1.z * w1b.z + v1.w * w1b.w;
#pragma unroll
      for (int msk = 8; msk >= 1; msk >>= 1) pq += __shfl_xor(pq, msk, 64);
      if ((lane & 15) == 0) a_ques_s[row] = pq;
      short8 pk;
      pk[0] = (short)f2bf(v0.x * w2a.x); pk[1] = (short)f2bf(v0.y * w2a.y);
      pk[2] = (short)f2bf(v0.z * w2a.z); pk[3] = (short)f2bf(v0.w * w2a.w);
      pk[4] = (short)f2bf(v1.x * w2b.x); pk[5] = (short)f2bf(v1.y * w2b.y);
      pk[6] = (short)f2bf(v1.z * w2b.z); pk[7] = (short)f2bf(v1.w * w2b.w);
      *(short8*)(xqs + row * PADW + (u << 3)) = pk;
    }
  }

  const int qlen = qlen_p[b];
  const int clen = clen_p[b];

  __syncthreads();

  float ac[4], aq[8];
#pragma unroll
  for (int reg = 0; reg < 4; ++reg)
    ac[reg] = a_cont_s[w * 16 + kb * 4 + reg];
#pragma unroll
  for (int n = 0; n < 8; ++n) aq[n] = a_ques_s[n * 16 + frow];

  // ---- main MFMA: S-tile 16c x 128q per wave ----
  floatx4 acc[8];
#pragma unroll
  for (int n = 0; n < 8; ++n) acc[n] = (floatx4){0.f, 0.f, 0.f, 0.f};
  const unsigned short* arow = xcs + (w * 16 + frow) * PADW + kb * 8;
  const unsigned short* brow = xqs + frow * PADW + kb * 8;
#pragma unroll
  for (int ks = 0; ks < 4; ++ks) {
    const short8 af = *(const short8*)(arow + ks * 32);
#pragma unroll
    for (int n = 0; n < 8; ++n) {
      const short8 bf = *(const short8*)(brow + n * 16 * PADW + ks * 32);
      acc[n] = __builtin_amdgcn_mfma_f32_16x16x32_bf16(af, bf, acc[n], 0, 0, 0);
    }
  }

  // ---- xcT emission from xcs (read-only; no barrier needed) ----
  {
    const int d = t & 127;
    const int half = t >> 7;
    __align__(16) unsigned short tmp[32];
#pragma unroll
    for (int j = 0; j < 32; ++j)
      tmp[j] = xcs[((half << 5) + j) * PADW + d];
    unsigned short* dp = xcT + ((size_t)b * DD + d) * LC + c0 + (half << 5);
#pragma unroll
    for (int j = 0; j < 4; ++j)
      *(short8*)(dp + (j << 3)) = *(const short8*)(tmp + (j << 3));
  }

  float raw[8][4];
#pragma unroll
  for (int n = 0; n < 8; ++n)
#pragma unroll
    for (int reg = 0; reg < 4; ++reg) raw[n][reg] = acc[n][reg] + ac[reg] + aq[n];

  // ---- q-masked softmax scalars (m, inv) per c-row ----
  float mreg[4], invreg[4];
#pragma unroll
  for (int reg = 0; reg < 4; ++reg) {
    float x[8];
    float m = -3.4e38f;
#pragma unroll
    for (int n = 0; n < 8; ++n) {
      x[n] = raw[n][reg] - ((n * 16 + frow) < qlen ? 0.f : NEG_BIG);
      m = fmaxf(m, x[n]);
    }
#pragma unroll
    for (int msk = 8; msk >= 1; msk >>= 1) m = fmaxf(m, __shfl_xor(m, msk, 64));
    float s = 0.f;
#pragma unroll
    for (int n = 0; n < 8; ++n) s += __expf(x[n] - m);
#pragma unroll
    for (int msk = 8; msk >= 1; msk >>= 1) s += __shfl_xor(s, msk, 64);
    mreg[reg] = m;
    invreg[reg] = 1.0f / s;
  }

  // ---- sbarb bf16 [c][q] + out_sbar f32, ONE full-width phase ----
  __syncthreads();  // xqs (ptile) dead after MFMA across all waves
#pragma unroll
  for (int reg = 0; reg < 4; ++reg) {
    const int crow = w * 16 + kb * 4 + reg;
    const float m = mreg[reg], inv = invreg[reg];
#pragma unroll
    for (int n = 0; n < 8; ++n) {
      const float xv = raw[n][reg] - ((n * 16 + frow) < qlen ? 0.f : NEG_BIG);
      ptile[crow * 136 + (n << 4) + frow] = f2bf(__expf(xv - m) * inv);
    }
  }
  __syncthreads();
  {
    const int row = t >> 2;      // c-local 0..127
    const int ch = t & 3;        // 32-q chunk
    unsigned short* sb_out = sbarb + ((size_t)b * LC + c0 + row) * LQ + (ch << 5);
    float* sf_out = out_sbar + ((size_t)b * LC + c0 + row) * LQ + (ch << 5);
#pragma unroll
    for (int k = 0; k < 4; ++k) {
      const short8 v = *(const short8*)(ptile + row * 136 + (ch << 5) + (k << 3));
      *(short8*)(sb_out + (k << 3)) = v;
      float4 f0, f1;
      f0.x = bf2f((unsigned short)v[0]); f0.y = bf2f((unsigned short)v[1]);
      f0.z = bf2f((unsigned short)v[2]); f0.w = bf2f((unsigned short)v[3]);
      f1.x = bf2f((unsigned short)v[4]); f1.y = bf2f((unsigned short)v[5]);
      f1.z = bf2f((unsigned short)v[6]); f1.w = bf2f((unsigned short)v[7]);
      *(float4*)(sf_out + (k << 3)) = f0;
      *(float4*)(sf_out + (k << 3) + 4) = f1;
    }
  }

  // ---- c-masked exp (no max subtraction; |S| ~ O(10)) ----
  const int cl0 = c0 + w * 16 + kb * 4;
#pragma unroll
  for (int reg = 0; reg < 4; ++reg) {
    const bool ok = (cl0 + reg) < clen;
#pragma unroll
    for (int n = 0; n < 8; ++n)
      raw[n][reg] = ok ? __expf(raw[n][reg]) : 0.f;
  }

  // ---- Pb [q][c] bf16, ONE full-width phase + colsum partials ----
  __syncthreads();
#pragma unroll
  for (int n = 0; n < 8; ++n) {
#pragma unroll
    for (int reg = 0; reg < 4; ++reg)
      ptile[((n << 4) + frow) * 136 + w * 16 + kb * 4 + reg] =
          f2bf(raw[n][reg]);
  }
  __syncthreads();
  {
    const int row = t >> 2;      // q-row 0..127
    const int ch = t & 3;        // 32-c chunk
    unsigned short* dst = Pb + ((size_t)b * LQ + row) * LC + c0 + (ch << 5);
    float s = 0.f;
#pragma unroll
    for (int k = 0; k < 4; ++k) {
      const short8 v = *(const short8*)(ptile + row * 136 + (ch << 5) + (k << 3));
      *(short8*)(dst + (k << 3)) = v;
#pragma unroll
      for (int j = 0; j < 8; ++j) s += bf2f((unsigned short)v[j]);
    }
    s += __shfl_xor(s, 1, 64);
    s += __shfl_xor(s, 2, 64);
    if (ch == 0) colsum_part[((size_t)b * 8 + ct) * LQ + row] = s;
  }
}

// ---------------------------------------------------------------------------
// K_fuse: per (b, 16-q tile): stage Pb rows in LDS once; inv from colsum
// partials; write normalized S_T (f32 output); xqT emission for its q-rows
// (distributed, aliased in abt region); A-GEMM with B-fragments DIRECT from
// global xcT (no K-loop barriers); AbT bf16 out.
// ---------------------------------------------------------------------------
__global__ __launch_bounds__(256) void k_fuse(
    const unsigned short* __restrict__ Pb, const float* __restrict__ colsum_part,
    const unsigned short* __restrict__ xcT, const float* __restrict__ xq,
    float* __restrict__ st, unsigned short* __restrict__ xqT,
    unsigned short* __restrict__ AbT) {
  __shared__ __align__(16) unsigned short Ps[16 * 1032];  // 33024 B
  __shared__ __align__(16) unsigned short abt[128 * 20];  // 5120 B (2 uses)
  __shared__ float inv_s[16];
  unsigned short* xqtile = abt;  // [16][136] u16 = 4352 B, dead before abt use

  const int b = blockIdx.x >> 3;
  const int q0 = (blockIdx.x & 7) << 4;
  const int t = threadIdx.x;
  const int w = t >> 6, lane = t & 63;
  const int frow = lane & 15, kb = lane >> 4;

  // stage P rows (16 x 1024 bf16) + xq tile (16 q x 128 d bf16)
  const unsigned short* Pb_blk = Pb + ((size_t)b * LQ + q0) * LC;
  {
    const int row = t >> 4;
#pragma unroll
    for (int j = 0; j < 8; ++j) {
      const int cs = ((t & 15) << 3) + (j << 7);
      *(short8*)(Ps + row * 1032 + cs) =
          *(const short8*)(Pb_blk + (size_t)row * LC + cs);
    }
  }
  {
    const int qrow = t >> 4, dch = t & 15;
    const float4 v0 =
        *(const float4*)(xq + ((size_t)b * LQ + q0 + qrow) * DD + (dch << 3));
    const float4 v1 =
        *(const float4*)(xq + ((size_t)b * LQ + q0 + qrow) * DD + (dch << 3) + 4);
    short8 pk;
    pk[0] = (short)f2bf(v0.x); pk[1] = (short)f2bf(v0.y);
    pk[2] = (short)f2bf(v0.z); pk[3] = (short)f2bf(v0.w);
    pk[4] = (short)f2bf(v1.x); pk[5] = (short)f2bf(v1.y);
    pk[6] = (short)f2bf(v1.z); pk[7] = (short)f2bf(v1.w);
    *(short8*)(xqtile + qrow * 136 + (dch << 3)) = pk;
  }
  if (t < 16) {
    float s = 0.f;
#pragma unroll
    for (int j = 0; j < 8; ++j)
      s += colsum_part[((size_t)b * 8 + j) * LQ + q0 + t];
    inv_s[t] = 1.0f / s;
  }
  __syncthreads();

  // xqT emission: d = t>>1, half = t&1 -> 8 q per thread
  {
    const int d = t >> 1, half = t & 1;
    __align__(16) unsigned short tmp[8];
#pragma unroll
    for (int j = 0; j < 8; ++j)
      tmp[j] = xqtile[((half << 3) + j) * 136 + d];
    *(short8*)(xqT + ((size_t)b * DD + d) * LQ + q0 + (half << 3)) =
        *(const short8*)(tmp);
  }

  // normalized S_T write (f32), fully coalesced
  {
    const int row = t >> 4;
    const float inv = inv_s[row];
    float* dst = st + ((size_t)b * LQ + q0 + row) * LC;
#pragma unroll
    for (int j = 0; j < 8; ++j) {
      const int cs = ((t & 15) << 3) + (j << 7);
      const short8 pv = *(const short8*)(Ps + row * 1032 + cs);
      float4 o0, o1;
      o0.x = bf2f((unsigned short)pv[0]) * inv;
      o0.y = bf2f((unsigned short)pv[1]) * inv;
      o0.z = bf2f((unsigned short)pv[2]) * inv;
      o0.w = bf2f((unsigned short)pv[3]) * inv;
      o1.x = bf2f((unsigned short)pv[4]) * inv;
      o1.y = bf2f((unsigned short)pv[5]) * inv;
      o1.z = bf2f((unsigned short)pv[6]) * inv;
      o1.w = bf2f((unsigned short)pv[7]) * inv;
      *(float4*)(dst + cs) = o0;
      *(float4*)(dst + cs + 4) = o1;
    }
  }

  // A-GEMM: A[q][d] = sum_c P[q][c] * xc[c][d]; B-frags direct from global.
  const unsigned short* xcT_b = xcT + (size_t)b * DD * LC;
  const unsigned short* b0p =
      xcT_b + (size_t)((w * 2 + 0) * 16 + frow) * LC + kb * 8;
  const unsigned short* b1p =
      xcT_b + (size_t)((w * 2 + 1) * 16 + frow) * LC + kb * 8;
  const unsigned short* ap = Ps + frow * 1032 + kb * 8;
  floatx4 acc0 = (floatx4){0.f, 0.f, 0.f, 0.f};
  floatx4 acc1 = (floatx4){0.f, 0.f, 0.f, 0.f};
#pragma unroll 8
  for (int kk = 0; kk < 32; ++kk) {
    const short8 af = *(const short8*)(ap + kk * 32);
    const short8 b0 = *(const short8*)(b0p + kk * 32);
    const short8 b1 = *(const short8*)(b1p + kk * 32);
    acc0 = __builtin_amdgcn_mfma_f32_16x16x32_bf16(af, b0, acc0, 0, 0, 0);
    acc1 = __builtin_amdgcn_mfma_f32_16x16x32_bf16(af, b1, acc1, 0, 0, 0);
  }

  __syncthreads();
  const float i0 = inv_s[kb * 4 + 0], i1 = inv_s[kb * 4 + 1];
  const float i2 = inv_s[kb * 4 + 2], i3 = inv_s[kb * 4 + 3];
  {
    const int d0 = (w * 2 + 0) * 16 + frow;
    abt[d0 * 20 + kb * 4 + 0] = f2bf(acc0[0] * i0);
    abt[d0 * 20 + kb * 4 + 1] = f2bf(acc0[1] * i1);
    abt[d0 * 20 + kb * 4 + 2] = f2bf(acc0[2] * i2);
    abt[d0 * 20 + kb * 4 + 3] = f2bf(acc0[3] * i3);
    const int d1 = (w * 2 + 1) * 16 + frow;
    abt[d1 * 20 + kb * 4 + 0] = f2bf(acc1[0] * i0);
    abt[d1 * 20 + kb * 4 + 1] = f2bf(acc1[1] * i1);
    abt[d1 * 20 + kb * 4 + 2] = f2bf(acc1[2] * i2);
    abt[d1 * 20 + kb * 4 + 3] = f2bf(acc1[3] * i3);
  }
  __syncthreads();
  const int d = t >> 1, h = t & 1;
  short8 ov;
#pragma unroll
  for (int j = 0; j < 8; ++j)
    ((unsigned short*)&ov)[j] = abt[d * 20 + h * 8 + j];
  *(short8*)(AbT + ((size_t)b * DD + d) * LQ + q0 + h * 8) = ov;
}

// ---------------------------------------------------------------------------
// K_out (MFMA): c2q = Sbar@xq, q2c = Sbar@A. A-frags straight from global
// sbarb bf16. LDS-staged coalesced epilogue.
// ---------------------------------------------------------------------------
__global__ __launch_bounds__(256) void k_out(
    const float* __restrict__ xc, const unsigned short* __restrict__ sbarb,
    const unsigned short* __restrict__ xqT, const unsigned short* __restrict__ AbT,
    float* __restrict__ out) {
  __shared__ __align__(16) float stg[2 * 32 * 132];  // 33792 B

  const int b = blockIdx.x >> 4;
  const int c0 = (blockIdx.x & 15) << 6;
  const int t = threadIdx.x;
  const int w = t >> 6, lane = t & 63;
  const int frow = lane & 15, kb = lane >> 4;

  const unsigned short* sb_blk = sbarb + ((size_t)b * LC + c0) * LQ;
  const unsigned short* xqT_b = xqT + (size_t)b * DD * LQ;
  const unsigned short* AbT_b = AbT + (size_t)b * DD * LQ;
  short8 bq[2][4], ba[2][4];
#pragma unroll
  for (int nt = 0; nt < 2; ++nt) {
    const int d = (w << 5) + (nt << 4) + frow;
#pragma unroll
    for (int ks = 0; ks < 4; ++ks) {
      bq[nt][ks] = *(const short8*)(xqT_b + (size_t)d * LQ + ks * 32 + kb * 8);
      ba[nt][ks] = *(const short8*)(AbT_b + (size_t)d * LQ + ks * 32 + kb * 8);
    }
  }

  floatx4 accq[4][2], acca[4][2];
#pragma unroll
  for (int mt = 0; mt < 4; ++mt)
#pragma unroll
    for (int nt = 0; nt < 2; ++nt) {
      accq[mt][nt] = (floatx4){0.f, 0.f, 0.f, 0.f};
      acca[mt][nt] = (floatx4){0.f, 0.f, 0.f, 0.f};
    }
#pragma unroll
  for (int mt = 0; mt < 4; ++mt) {
#pragma unroll
    for (int ks = 0; ks < 4; ++ks) {
      const short8 af = *(const short8*)(
          sb_blk + (size_t)((mt << 4) + frow) * LQ + ks * 32 + kb * 8);
#pragma unroll
      for (int nt = 0; nt < 2; ++nt) {
        accq[mt][nt] =
            __builtin_amdgcn_mfma_f32_16x16x32_bf16(af, bq[nt][ks], accq[mt][nt], 0, 0, 0);
        acca[mt][nt] =
            __builtin_amdgcn_mfma_f32_16x16x32_bf16(af, ba[nt][ks], acca[mt][nt], 0, 0, 0);
      }
    }
  }

  float* out_b = out + ((size_t)b * LC + c0) * (4 * DD);
  const float* xc_blk = xc + ((size_t)b * LC + c0) * DD;

#pragma unroll
  for (int p = 0; p < 2; ++p) {
    __syncthreads();
#pragma unroll
    for (int mh = 0; mh < 2; ++mh) {
      const int mt = 2 * p + mh;
#pragma unroll
      for (int nt = 0; nt < 2; ++nt) {
        const int d = (w << 5) + (nt << 4) + frow;
        const int cl = (mh << 4) + (kb << 2);
#pragma unroll
        for (int reg = 0; reg < 4; ++reg) {
          stg[(cl + reg) * 132 + d] = accq[mt][nt][reg];
          stg[32 * 132 + (cl + reg) * 132 + d] = acca[mt][nt][reg];
        }
      }
    }
    __syncthreads();
    const int g = lane >> 4;
    const int d0 = (lane & 15) << 3;
#pragma unroll
    for (int j = 0; j < 8; ++j) {
      const int rl = (w << 3) + j;
      const int c = (p << 5) + rl;
      const float4 xv0 = *(const float4*)(xc_blk + (size_t)c * DD + d0);
      const float4 xv1 = *(const float4*)(xc_blk + (size_t)c * DD + d0 + 4);
      const float4 cq0 = *(const float4*)(stg + rl * 132 + d0);
      const float4 cq1 = *(const float4*)(stg + rl * 132 + d0 + 4);
      const float4 qc0 = *(const float4*)(stg + 32 * 132 + rl * 132 + d0);
      const float4 qc1 = *(const float4*)(stg + 32 * 132 + rl * 132 + d0 + 4);
      float4 o0, o1;
      if (g == 0) { o0 = xv0; o1 = xv1; }
      else if (g == 1) { o0 = cq0; o1 = cq1; }
      else if (g == 2) {
        o0 = make_float4(xv0.x * cq0.x, xv0.y * cq0.y, xv0.z * cq0.z, xv0.w * cq0.w);
        o1 = make_float4(xv1.x * cq1.x, xv1.y * cq1.y, xv1.z * cq1.z, xv1.w * cq1.w);
      } else {
        o0 = make_float4(xv0.x * qc0.x, xv0.y * qc0.y, xv0.z * qc0.z, xv0.w * qc0.w);
        o1 = make_float4(xv1.x * qc1.x, xv1.y * qc1.y, xv1.z * qc1.z, xv1.w * qc1.w);
      }
      float* o = out_b + (size_t)c * (4 * DD) + (g << 7) + d0;
      *(float4*)(o) = o0;
      *(float4*)(o + 4) = o1;
    }
  }
}

extern "C" void kernel_launch(void* const* d_in, const int* in_sizes, int n_in,
                              void* d_out, int out_size, void* d_ws, size_t ws_size,
                              hipStream_t stream) {
  const float* xc = (const float*)d_in[0];
  const float* xq = (const float*)d_in[1];
  const float* W0 = (const float*)d_in[2];
  const float* W1 = (const float*)d_in[3];
  const float* W2 = (const float*)d_in[4];
  const int* clen = (const int*)d_in[5];
  const int* qlen = (const int*)d_in[6];

  float* out = (float*)d_out;
  float* out_sbar = out + (size_t)NB * LC * 4 * DD;
  float* out_st = out_sbar + (size_t)NB * LC * LQ;

  float* colsum_part = (float*)d_ws;                         // 64K f32
  unsigned short* xcT = (unsigned short*)(colsum_part + NB * 8 * LQ);  // 8.4M u16
  unsigned short* xqT = xcT + (size_t)NB * LC * DD;          // 1M u16
  unsigned short* AbT = xqT + (size_t)NB * LQ * DD;          // 1M u16
  unsigned short* Pb = AbT + (size_t)NB * LQ * DD;           // 8.4M u16
  unsigned short* sbarb = Pb + (size_t)NB * LQ * LC;         // 8.4M u16

  k_score<<<NB * 8, 512, 0, stream>>>(xc, xq, W2, W0, W1, qlen, clen,
                                      out_sbar, Pb, colsum_part, xcT, sbarb);
  k_fuse<<<NB * 8, 256, 0, stream>>>(Pb, colsum_part, xcT, xq, out_st, xqT,
                                     AbT);
  k_out<<<NB * 16, 256, 0, stream>>>(xc, sbarb, xqT, AbT, out);
}

// Round 12
// 114.219 us; speedup vs baseline: 1.1153x; 1.1153x over previous
//
#include <hip/hip_runtime.h>

#define NB 64
#define LC 1024
#define LQ 128
#define DD 128
#define NEG_BIG 1.0e12f

typedef __attribute__((ext_vector_type(8))) short short8;
typedef __attribute__((ext_vector_type(4))) unsigned short ushort4v;
typedef __attribute__((ext_vector_type(4))) float floatx4;

__device__ __forceinline__ unsigned short f2bf(float f) {
  union { float f; unsigned int u; } v;
  v.f = f;
  const unsigned int r = v.u + 0x7FFFu + ((v.u >> 16) & 1u);
  return (unsigned short)(r >> 16);
}
__device__ __forceinline__ float bf2f(unsigned int u) {
  union { unsigned int u; float f; } v;
  v.u = u << 16;
  return v.f;
}

// ---------------------------------------------------------------------------
// K_score (MFMA), per (b, 128-c tile):
//   S = a_cont + a_ques + (xc.W2) xq^T ; a_cont AND a_ques inline;
//   xcT emitted from LDS tile; xqT emitted by ct==0 blocks (tail phase)
//   - q-masked softmax -> out_sbar (f32) + sbarb bf16 [c][q]
//   - Pb[b][q][c] = (c<clen ? exp(S) : 0) bf16 + colsum partials
// ---------------------------------------------------------------------------
#define PADW 136

__global__ __launch_bounds__(512) void k_score(
    const float* __restrict__ xc, const float* __restrict__ xq,
    const float* __restrict__ w2, const float* __restrict__ W0,
    const float* __restrict__ W1, const int* __restrict__ qlen_p,
    const int* __restrict__ clen_p, float* __restrict__ out_sbar,
    unsigned short* __restrict__ Pb, float* __restrict__ colsum_part,
    unsigned short* __restrict__ xcT, unsigned short* __restrict__ xqT,
    unsigned short* __restrict__ sbarb) {
  __shared__ __align__(16) unsigned short smem[2 * 128 * PADW];  // 69632 B
  __shared__ float a_cont_s[128];
  __shared__ float a_ques_s[128];
  unsigned short* xcs = smem;                  // plain xc tile [128][PADW]
  unsigned short* xqs = smem + 128 * PADW;     // xq*W2 tile [128][PADW]
  unsigned short* ptile = smem + 128 * PADW;   // reuse after MFMA

  const int b = blockIdx.x >> 3;
  const int ct = blockIdx.x & 7;
  const int c0 = ct << 7;
  const int t = threadIdx.x;
  const int w = t >> 6, lane = t & 63;
  const int frow = lane & 15;
  const int kb = lane >> 4;

  const float* xc_blk = xc + ((size_t)b * LC + c0) * DD;
  const float* xq_b = xq + (size_t)b * LQ * DD;

  // per-thread fixed d-chunk (u = t & 15 invariant across i)
  const int u = t & 15;
  const float4 w0a = *(const float4*)(W0 + (u << 3));
  const float4 w0b = *(const float4*)(W0 + (u << 3) + 4);
  const float4 w1a = *(const float4*)(W1 + (u << 3));
  const float4 w1b = *(const float4*)(W1 + (u << 3) + 4);
  const float4 w2a = *(const float4*)(w2 + (u << 3));
  const float4 w2b = *(const float4*)(w2 + (u << 3) + 4);

  // ---- stage xc (bf16, + a_cont partials) and xq*W2 (bf16, + a_ques) ----
#pragma unroll
  for (int i = 0; i < 4; ++i) {
    const int row = (t >> 4) + (i << 5);
    {
      const float4 v0 = *(const float4*)(xc_blk + (size_t)row * DD + (u << 3));
      const float4 v1 = *(const float4*)(xc_blk + (size_t)row * DD + (u << 3) + 4);
      short8 pk;
      pk[0] = (short)f2bf(v0.x); pk[1] = (short)f2bf(v0.y);
      pk[2] = (short)f2bf(v0.z); pk[3] = (short)f2bf(v0.w);
      pk[4] = (short)f2bf(v1.x); pk[5] = (short)f2bf(v1.y);
      pk[6] = (short)f2bf(v1.z); pk[7] = (short)f2bf(v1.w);
      *(short8*)(xcs + row * PADW + (u << 3)) = pk;
      float pd = v0.x * w0a.x + v0.y * w0a.y + v0.z * w0a.z + v0.w * w0a.w +
                 v1.x * w0b.x + v1.y * w0b.y + v1.z * w0b.z + v1.w * w0b.w;
#pragma unroll
      for (int msk = 8; msk >= 1; msk >>= 1) pd += __shfl_xor(pd, msk, 64);
      if ((lane & 15) == 0) a_cont_s[row] = pd;
    }
    {
      const float4 v0 = *(const float4*)(xq_b + (size_t)row * DD + (u << 3));
      const float4 v1 = *(const float4*)(xq_b + (size_t)row * DD + (u << 3) + 4);
      float pq = v0.x * w1a.x + v0.y * w1a.y + v0.z * w1a.z + v0.w * w1a.w +
                 v1.x * w1b.x + v1.y * w1b.y + v1.z * w1b.z + v1.w * w1b.w;
#pragma unroll
      for (int msk = 8; msk >= 1; msk >>= 1) pq += __shfl_xor(pq, msk, 64);
      if ((lane & 15) == 0) a_ques_s[row] = pq;
      short8 pk;
      pk[0] = (short)f2bf(v0.x * w2a.x); pk[1] = (short)f2bf(v0.y * w2a.y);
      pk[2] = (short)f2bf(v0.z * w2a.z); pk[3] = (short)f2bf(v0.w * w2a.w);
      pk[4] = (short)f2bf(v1.x * w2b.x); pk[5] = (short)f2bf(v1.y * w2b.y);
      pk[6] = (short)f2bf(v1.z * w2b.z); pk[7] = (short)f2bf(v1.w * w2b.w);
      *(short8*)(xqs + row * PADW + (u << 3)) = pk;
    }
  }

  const int qlen = qlen_p[b];
  const int clen = clen_p[b];

  __syncthreads();

  float ac[4], aq[8];
#pragma unroll
  for (int reg = 0; reg < 4; ++reg)
    ac[reg] = a_cont_s[w * 16 + kb * 4 + reg];
#pragma unroll
  for (int n = 0; n < 8; ++n) aq[n] = a_ques_s[n * 16 + frow];

  // ---- main MFMA: S-tile 16c x 128q per wave ----
  floatx4 acc[8];
#pragma unroll
  for (int n = 0; n < 8; ++n) acc[n] = (floatx4){0.f, 0.f, 0.f, 0.f};
  const unsigned short* arow = xcs + (w * 16 + frow) * PADW + kb * 8;
  const unsigned short* brow = xqs + frow * PADW + kb * 8;
#pragma unroll
  for (int ks = 0; ks < 4; ++ks) {
    const short8 af = *(const short8*)(arow + ks * 32);
#pragma unroll
    for (int n = 0; n < 8; ++n) {
      const short8 bf = *(const short8*)(brow + n * 16 * PADW + ks * 32);
      acc[n] = __builtin_amdgcn_mfma_f32_16x16x32_bf16(af, bf, acc[n], 0, 0, 0);
    }
  }

  // ---- xcT emission from xcs (read-only; no barrier needed) ----
  {
    const int d = t & 127;
    const int half = t >> 7;
    __align__(16) unsigned short tmp[32];
#pragma unroll
    for (int j = 0; j < 32; ++j)
      tmp[j] = xcs[((half << 5) + j) * PADW + d];
    unsigned short* dp = xcT + ((size_t)b * DD + d) * LC + c0 + (half << 5);
#pragma unroll
    for (int j = 0; j < 4; ++j)
      *(short8*)(dp + (j << 3)) = *(const short8*)(tmp + (j << 3));
  }

  float raw[8][4];
#pragma unroll
  for (int n = 0; n < 8; ++n)
#pragma unroll
    for (int reg = 0; reg < 4; ++reg) raw[n][reg] = acc[n][reg] + ac[reg] + aq[n];

  // ---- q-masked softmax -> sbar f32; keep per-reg m, inv ----
  float mreg[4], invreg[4];
  float* sbar_row0 =
      out_sbar + ((size_t)b * LC + c0 + w * 16 + kb * 4) * LQ + frow;
#pragma unroll
  for (int reg = 0; reg < 4; ++reg) {
    float x[8];
    float m = -3.4e38f;
#pragma unroll
    for (int n = 0; n < 8; ++n) {
      x[n] = raw[n][reg] - ((n * 16 + frow) < qlen ? 0.f : NEG_BIG);
      m = fmaxf(m, x[n]);
    }
#pragma unroll
    for (int msk = 8; msk >= 1; msk >>= 1) m = fmaxf(m, __shfl_xor(m, msk, 64));
    float s = 0.f;
#pragma unroll
    for (int n = 0; n < 8; ++n) {
      x[n] = __expf(x[n] - m);
      s += x[n];
    }
#pragma unroll
    for (int msk = 8; msk >= 1; msk >>= 1) s += __shfl_xor(s, msk, 64);
    const float inv = 1.0f / s;
    float* o = sbar_row0 + (size_t)reg * LQ;
#pragma unroll
    for (int n = 0; n < 8; ++n) o[n * 16] = x[n] * inv;
    mreg[reg] = m;
    invreg[reg] = inv;
  }

  // ---- sbarb bf16 [c][q] phases ----
  unsigned short* sb_out = sbarb + ((size_t)b * LC + c0) * LQ;
#pragma unroll
  for (int p = 0; p < 4; ++p) {
    __syncthreads();
    if ((w >> 1) == p) {
      const int crow = ((w & 1) << 4) + (kb << 2);
#pragma unroll
      for (int reg = 0; reg < 4; ++reg) {
        const float m = mreg[reg], inv = invreg[reg];
#pragma unroll
        for (int n = 0; n < 8; ++n) {
          const float xv = raw[n][reg] - ((n * 16 + frow) < qlen ? 0.f : NEG_BIG);
          ptile[(crow + reg) * 136 + (n << 4) + frow] = f2bf(__expf(xv - m) * inv);
        }
      }
    }
    __syncthreads();
    const int row = t >> 4, ch = t & 15;
    *(short8*)(sb_out + (size_t)((p << 5) + row) * LQ + (ch << 3)) =
        *(const short8*)(ptile + row * 136 + (ch << 3));
  }

  // ---- c-masked exp (no max subtraction; |S| ~ O(10)) ----
  const int cl0 = c0 + w * 16 + kb * 4;
#pragma unroll
  for (int reg = 0; reg < 4; ++reg) {
    const bool ok = (cl0 + reg) < clen;
#pragma unroll
    for (int n = 0; n < 8; ++n)
      raw[n][reg] = ok ? __expf(raw[n][reg]) : 0.f;
  }

  // ---- Pb transposed write (bf16) + column-sum partials ----
  unsigned short* Pb_b = Pb + (size_t)b * LQ * LC;
  float* cs_blk = colsum_part + ((size_t)b * 8 + ct) * LQ;
#pragma unroll
  for (int p = 0; p < 4; ++p) {
    __syncthreads();
#pragma unroll
    for (int n2 = 0; n2 < 2; ++n2) {
#pragma unroll
      for (int reg = 0; reg < 4; ++reg)
        ptile[(n2 * 16 + frow) * 136 + (w * 16 + kb * 4 + reg)] =
            f2bf(raw[2 * p + n2][reg]);
    }
    __syncthreads();
    const int qrow = t >> 4;
    const int ch = t & 15;
    const short8 pv = *(const short8*)(ptile + qrow * 136 + (ch << 3));
    *(short8*)(Pb_b + (size_t)(p * 32 + qrow) * LC + c0 + (ch << 3)) = pv;
    float s = 0.f;
#pragma unroll
    for (int j = 0; j < 8; ++j) s += bf2f((unsigned short)pv[j]);
#pragma unroll
    for (int msk = 8; msk >= 1; msk >>= 1) s += __shfl_xor(s, msk, 64);
    if (ch == 0) cs_blk[p * 32 + qrow] = s;
  }

  // ---- xqT emission tail by ct==0 blocks (ptile free now) ----
  if (ct == 0) {
    __syncthreads();
#pragma unroll
    for (int i = 0; i < 4; ++i) {
      const int id = t + (i << 9);
      const int row = id >> 4, uu = id & 15;
      const float4 v0 = *(const float4*)(xq_b + (size_t)row * DD + (uu << 3));
      const float4 v1 = *(const float4*)(xq_b + (size_t)row * DD + (uu << 3) + 4);
      short8 pk;
      pk[0] = (short)f2bf(v0.x); pk[1] = (short)f2bf(v0.y);
      pk[2] = (short)f2bf(v0.z); pk[3] = (short)f2bf(v0.w);
      pk[4] = (short)f2bf(v1.x); pk[5] = (short)f2bf(v1.y);
      pk[6] = (short)f2bf(v1.z); pk[7] = (short)f2bf(v1.w);
      *(short8*)(ptile + row * 136 + (uu << 3)) = pk;
    }
    __syncthreads();
    const int d = t >> 2, ch4 = t & 3;
    __align__(16) unsigned short tmp2[32];
#pragma unroll
    for (int j = 0; j < 32; ++j)
      tmp2[j] = ptile[(ch4 * 32 + j) * 136 + d];
    unsigned short* dp = xqT + ((size_t)b * DD + d) * LQ + ch4 * 32;
#pragma unroll
    for (int j = 0; j < 4; ++j)
      *(short8*)(dp + (j << 3)) = *(const short8*)(tmp2 + (j << 3));
  }
}

// ---------------------------------------------------------------------------
// K_fuse: per (b, 16-q tile): stage Pb rows in LDS once; inv from colsum
// partials; write normalized S_T (f32 output); A-GEMM with B-fragments loaded
// DIRECTLY from global xcT (no K-loop barriers); AbT bf16 out.
// ---------------------------------------------------------------------------
__global__ __launch_bounds__(256) void k_fuse(
    const unsigned short* __restrict__ Pb, const float* __restrict__ colsum_part,
    const unsigned short* __restrict__ xcT, float* __restrict__ st,
    unsigned short* __restrict__ AbT) {
  __shared__ __align__(16) unsigned short Ps[16 * 1032];  // 33024 B
  __shared__ unsigned short abt[128 * 20];                // 5120 B
  __shared__ float inv_s[16];

  const int b = blockIdx.x >> 3;
  const int q0 = (blockIdx.x & 7) << 4;
  const int t = threadIdx.x;
  const int w = t >> 6, lane = t & 63;
  const int frow = lane & 15, kb = lane >> 4;

  // stage P rows (16 x 1024 bf16) once
  const unsigned short* Pb_blk = Pb + ((size_t)b * LQ + q0) * LC;
  {
    const int row = t >> 4;
#pragma unroll
    for (int j = 0; j < 8; ++j) {
      const int cs = ((t & 15) << 3) + (j << 7);
      *(short8*)(Ps + row * 1032 + cs) =
          *(const short8*)(Pb_blk + (size_t)row * LC + cs);
    }
  }
  if (t < 16) {
    float s = 0.f;
#pragma unroll
    for (int j = 0; j < 8; ++j)
      s += colsum_part[((size_t)b * 8 + j) * LQ + q0 + t];
    inv_s[t] = 1.0f / s;
  }
  __syncthreads();

  // normalized S_T write (f32), fully coalesced
  {
    const int row = t >> 4;
    const float inv = inv_s[row];
    float* dst = st + ((size_t)b * LQ + q0 + row) * LC;
#pragma unroll
    for (int j = 0; j < 8; ++j) {
      const int cs = ((t & 15) << 3) + (j << 7);
      const short8 pv = *(const short8*)(Ps + row * 1032 + cs);
      float4 o0, o1;
      o0.x = bf2f((unsigned short)pv[0]) * inv;
      o0.y = bf2f((unsigned short)pv[1]) * inv;
      o0.z = bf2f((unsigned short)pv[2]) * inv;
      o0.w = bf2f((unsigned short)pv[3]) * inv;
      o1.x = bf2f((unsigned short)pv[4]) * inv;
      o1.y = bf2f((unsigned short)pv[5]) * inv;
      o1.z = bf2f((unsigned short)pv[6]) * inv;
      o1.w = bf2f((unsigned short)pv[7]) * inv;
      *(float4*)(dst + cs) = o0;
      *(float4*)(dst + cs + 4) = o1;
    }
  }

  // A-GEMM: A[q][d] = sum_c P[q][c] * xc[c][d]; B-frags direct from global.
  const unsigned short* xcT_b = xcT + (size_t)b * DD * LC;
  const unsigned short* b0p =
      xcT_b + (size_t)((w * 2 + 0) * 16 + frow) * LC + kb * 8;
  const unsigned short* b1p =
      xcT_b + (size_t)((w * 2 + 1) * 16 + frow) * LC + kb * 8;
  const unsigned short* ap = Ps + frow * 1032 + kb * 8;
  floatx4 acc0 = (floatx4){0.f, 0.f, 0.f, 0.f};
  floatx4 acc1 = (floatx4){0.f, 0.f, 0.f, 0.f};
#pragma unroll 8
  for (int kk = 0; kk < 32; ++kk) {
    const short8 af = *(const short8*)(ap + kk * 32);
    const short8 b0 = *(const short8*)(b0p + kk * 32);
    const short8 b1 = *(const short8*)(b1p + kk * 32);
    acc0 = __builtin_amdgcn_mfma_f32_16x16x32_bf16(af, b0, acc0, 0, 0, 0);
    acc1 = __builtin_amdgcn_mfma_f32_16x16x32_bf16(af, b1, acc1, 0, 0, 0);
  }

  __syncthreads();
  const float i0 = inv_s[kb * 4 + 0], i1 = inv_s[kb * 4 + 1];
  const float i2 = inv_s[kb * 4 + 2], i3 = inv_s[kb * 4 + 3];
  {
    const int d0 = (w * 2 + 0) * 16 + frow;
    abt[d0 * 20 + kb * 4 + 0] = f2bf(acc0[0] * i0);
    abt[d0 * 20 + kb * 4 + 1] = f2bf(acc0[1] * i1);
    abt[d0 * 20 + kb * 4 + 2] = f2bf(acc0[2] * i2);
    abt[d0 * 20 + kb * 4 + 3] = f2bf(acc0[3] * i3);
    const int d1 = (w * 2 + 1) * 16 + frow;
    abt[d1 * 20 + kb * 4 + 0] = f2bf(acc1[0] * i0);
    abt[d1 * 20 + kb * 4 + 1] = f2bf(acc1[1] * i1);
    abt[d1 * 20 + kb * 4 + 2] = f2bf(acc1[2] * i2);
    abt[d1 * 20 + kb * 4 + 3] = f2bf(acc1[3] * i3);
  }
  __syncthreads();
  const int d = t >> 1, h = t & 1;
  short8 ov;
#pragma unroll
  for (int j = 0; j < 8; ++j)
    ((unsigned short*)&ov)[j] = abt[d * 20 + h * 8 + j];
  *(short8*)(AbT + ((size_t)b * DD + d) * LQ + q0 + h * 8) = ov;
}

// ---------------------------------------------------------------------------
// K_out (MFMA): c2q = Sbar@xq, q2c = Sbar@A. A-frags straight from global
// sbarb bf16. LDS-staged coalesced epilogue.
// ---------------------------------------------------------------------------
__global__ __launch_bounds__(256) void k_out(
    const float* __restrict__ xc, const unsigned short* __restrict__ sbarb,
    const unsigned short* __restrict__ xqT, const unsigned short* __restrict__ AbT,
    float* __restrict__ out) {
  __shared__ __align__(16) float stg[2 * 32 * 132];  // 33792 B

  const int b = blockIdx.x >> 4;
  const int c0 = (blockIdx.x & 15) << 6;
  const int t = threadIdx.x;
  const int w = t >> 6, lane = t & 63;
  const int frow = lane & 15, kb = lane >> 4;

  const unsigned short* sb_blk = sbarb + ((size_t)b * LC + c0) * LQ;
  const unsigned short* xqT_b = xqT + (size_t)b * DD * LQ;
  const unsigned short* AbT_b = AbT + (size_t)b * DD * LQ;
  short8 bq[2][4], ba[2][4];
#pragma unroll
  for (int nt = 0; nt < 2; ++nt) {
    const int d = (w << 5) + (nt << 4) + frow;
#pragma unroll
    for (int ks = 0; ks < 4; ++ks) {
      bq[nt][ks] = *(const short8*)(xqT_b + (size_t)d * LQ + ks * 32 + kb * 8);
      ba[nt][ks] = *(const short8*)(AbT_b + (size_t)d * LQ + ks * 32 + kb * 8);
    }
  }

  floatx4 accq[4][2], acca[4][2];
#pragma unroll
  for (int mt = 0; mt < 4; ++mt)
#pragma unroll
    for (int nt = 0; nt < 2; ++nt) {
      accq[mt][nt] = (floatx4){0.f, 0.f, 0.f, 0.f};
      acca[mt][nt] = (floatx4){0.f, 0.f, 0.f, 0.f};
    }
#pragma unroll
  for (int mt = 0; mt < 4; ++mt) {
#pragma unroll
    for (int ks = 0; ks < 4; ++ks) {
      const short8 af = *(const short8*)(
          sb_blk + (size_t)((mt << 4) + frow) * LQ + ks * 32 + kb * 8);
#pragma unroll
      for (int nt = 0; nt < 2; ++nt) {
        accq[mt][nt] =
            __builtin_amdgcn_mfma_f32_16x16x32_bf16(af, bq[nt][ks], accq[mt][nt], 0, 0, 0);
        acca[mt][nt] =
            __builtin_amdgcn_mfma_f32_16x16x32_bf16(af, ba[nt][ks], acca[mt][nt], 0, 0, 0);
      }
    }
  }

  float* out_b = out + ((size_t)b * LC + c0) * (4 * DD);
  const float* xc_blk = xc + ((size_t)b * LC + c0) * DD;

#pragma unroll
  for (int p = 0; p < 2; ++p) {
    __syncthreads();
#pragma unroll
    for (int mh = 0; mh < 2; ++mh) {
      const int mt = 2 * p + mh;
#pragma unroll
      for (int nt = 0; nt < 2; ++nt) {
        const int d = (w << 5) + (nt << 4) + frow;
        const int cl = (mh << 4) + (kb << 2);
#pragma unroll
        for (int reg = 0; reg < 4; ++reg) {
          stg[(cl + reg) * 132 + d] = accq[mt][nt][reg];
          stg[32 * 132 + (cl + reg) * 132 + d] = acca[mt][nt][reg];
        }
      }
    }
    __syncthreads();
    const int g = lane >> 4;
    const int d0 = (lane & 15) << 3;
#pragma unroll
    for (int j = 0; j < 8; ++j) {
      const int rl = (w << 3) + j;
      const int c = (p << 5) + rl;
      const float4 xv0 = *(const float4*)(xc_blk + (size_t)c * DD + d0);
      const float4 xv1 = *(const float4*)(xc_blk + (size_t)c * DD + d0 + 4);
      const float4 cq0 = *(const float4*)(stg + rl * 132 + d0);
      const float4 cq1 = *(const float4*)(stg + rl * 132 + d0 + 4);
      const float4 qc0 = *(const float4*)(stg + 32 * 132 + rl * 132 + d0);
      const float4 qc1 = *(const float4*)(stg + 32 * 132 + rl * 132 + d0 + 4);
      float4 o0, o1;
      if (g == 0) { o0 = xv0; o1 = xv1; }
      else if (g == 1) { o0 = cq0; o1 = cq1; }
      else if (g == 2) {
        o0 = make_float4(xv0.x * cq0.x, xv0.y * cq0.y, xv0.z * cq0.z, xv0.w * cq0.w);
        o1 = make_float4(xv1.x * cq1.x, xv1.y * cq1.y, xv1.z * cq1.z, xv1.w * cq1.w);
      } else {
        o0 = make_float4(xv0.x * qc0.x, xv0.y * qc0.y, xv0.z * qc0.z, xv0.w * qc0.w);
        o1 = make_float4(xv1.x * qc1.x, xv1.y * qc1.y, xv1.z * qc1.z, xv1.w * qc1.w);
      }
      float* o = out_b + (size_t)c * (4 * DD) + (g << 7) + d0;
      *(float4*)(o) = o0;
      *(float4*)(o + 4) = o1;
    }
  }
}

extern "C" void kernel_launch(void* const* d_in, const int* in_sizes, int n_in,
                              void* d_out, int out_size, void* d_ws, size_t ws_size,
                              hipStream_t stream) {
  const float* xc = (const float*)d_in[0];
  const float* xq = (const float*)d_in[1];
  const float* W0 = (const float*)d_in[2];
  const float* W1 = (const float*)d_in[3];
  const float* W2 = (const float*)d_in[4];
  const int* clen = (const int*)d_in[5];
  const int* qlen = (const int*)d_in[6];

  float* out = (float*)d_out;
  float* out_sbar = out + (size_t)NB * LC * 4 * DD;
  float* out_st = out_sbar + (size_t)NB * LC * LQ;

  float* colsum_part = (float*)d_ws;                         // 64K f32
  unsigned short* xcT = (unsigned short*)(colsum_part + NB * 8 * LQ);  // 8.4M u16
  unsigned short* xqT = xcT + (size_t)NB * LC * DD;          // 1M u16
  unsigned short* AbT = xqT + (size_t)NB * LQ * DD;          // 1M u16
  unsigned short* Pb = AbT + (size_t)NB * LQ * DD;           // 8.4M u16
  unsigned short* sbarb = Pb + (size_t)NB * LQ * LC;         // 8.4M u16

  k_score<<<NB * 8, 512, 0, stream>>>(xc, xq, W2, W0, W1, qlen, clen,
                                      out_sbar, Pb, colsum_part, xcT, xqT,
                                      sbarb);
  k_fuse<<<NB * 8, 256, 0, stream>>>(Pb, colsum_part, xcT, out_st, AbT);
  k_out<<<NB * 16, 256, 0, stream>>>(xc, sbarb, xqT, AbT, out);
}